// Round 1
// baseline (190.637 us; speedup 1.0000x reference)
//
#include <hip/hip_runtime.h>
#include <cstdint>

// Problem constants
#define B_   64
#define CI_  384
#define CO_  384
#define HW_  784
#define E_   8

typedef unsigned short ushort_t;
typedef unsigned int   uint_t;

typedef __attribute__((ext_vector_type(8))) short bf16x8;   // 8 bf16 (4 VGPRs)
typedef __attribute__((ext_vector_type(4))) float f32x4;    // MFMA accumulator

__device__ __forceinline__ ushort_t f2bf_rne(float f) {
  uint_t u = __builtin_bit_cast(uint_t, f);
  u += 0x7fffu + ((u >> 16) & 1u);
  return (ushort_t)(u >> 16);
}

// Pack truncated-bf16 of (f0 -> low ushort, f1 -> high ushort) in one v_perm_b32.
// Truncation bias decorrelates across the K=384 sum (agg sign independent of x),
// net error ~0.01 — well under threshold, and 4x cheaper than RNE here.
__device__ __forceinline__ uint_t pack_bf16_trunc(float f0, float f1) {
  return __builtin_amdgcn_perm(__builtin_bit_cast(uint_t, f1),   // S0 -> bytes 4..7
                               __builtin_bit_cast(uint_t, f0),   // S1 -> bytes 0..3
                               0x07060302u);                     // {f1.b3,f1.b2,f0.b3,f0.b2}
}

// ---------------------------------------------------------------------------
// Kernel 1: agg[b,o,i] = sum_e r[b,e] * w[e,o,i], stored bf16 into workspace.
// 288 blocks x 256 thr; each block owns 512 consecutive (o,i) elements for ALL b
// -> weight read exactly once from HBM (4.7 MB), agg write 18.9 MB.
// ---------------------------------------------------------------------------
__global__ __launch_bounds__(256) void agg_kernel(const float* __restrict__ rw,
                                                  const float* __restrict__ w,
                                                  ushort_t* __restrict__ agg) {
  __shared__ float r[B_ * E_];  // 512 routing weights
  const int tid = threadIdx.x;
  r[tid]       = rw[tid];
  r[tid + 256] = rw[tid + 256];
  const int base = blockIdx.x * 512 + tid * 2;  // flat (o,i) pair index
  float2 wv[E_];
#pragma unroll
  for (int e = 0; e < E_; ++e)
    wv[e] = *(const float2*)&w[e * (CO_ * CI_) + base];
  __syncthreads();
#pragma unroll 4
  for (int b = 0; b < B_; ++b) {
    float ax = 0.f, ay = 0.f;
#pragma unroll
    for (int e = 0; e < E_; ++e) {
      const float rv = r[b * E_ + e];
      ax += rv * wv[e].x;
      ay += rv * wv[e].y;
    }
    const uint_t v = (uint_t)f2bf_rne(ax) | ((uint_t)f2bf_rne(ay) << 16);
    *(uint_t*)&agg[(size_t)b * (CO_ * CI_) + base] = v;
  }
}

// ---------------------------------------------------------------------------
// Kernel 2: per-sample GEMM  out[b] = agg[b](384x384, bf16) @ x[b](384x784, f32)
// BM=BN=128, BK=32, 256 thr = 4 waves in 2x2, each wave 64x64 (4x4 16x16 frags).
// A staged via global_load_lds width=16; B transpose-converted f32->bf16 into
// an [n][k] LDS tile with 80B row stride (conflict-free b128 frag reads).
// ---------------------------------------------------------------------------
#define BM 128
#define BN 128
#define BK 32
#define KIT (CI_ / BK)     // 12
#define BS_STRIDE 40       // ushorts per Bs row = 80 B (16B-aligned, stride 20 dw)

__global__ __launch_bounds__(256) void moe_gemm(const float* __restrict__ X,
                                                const ushort_t* __restrict__ Agg,
                                                float* __restrict__ Out) {
  __shared__ __align__(16) ushort_t As[BM * BK];         // [m][k], 64B rows (8 KB)
  __shared__ __align__(16) ushort_t Bs[BN * BS_STRIDE];  // [n][k], 80B rows (10 KB)

  const int tid  = threadIdx.x;
  const int lane = tid & 63;
  const int wave = tid >> 6;
  const int wm = wave & 1, wn = wave >> 1;
  const int b = blockIdx.z, mt = blockIdx.y, nt = blockIdx.x;

  const ushort_t* Ab = Agg + (size_t)b * CO_ * CI_ + mt * BM * CI_;
  const float*    Xb = X   + (size_t)b * CI_ * HW_;

  // B-staging coords: thread t handles n = t&127, k sub-offset (t>>7)*4
  const int sn  = tid & 127;
  const int sk4 = (tid >> 7) * 4;
  const int gn  = nt * BN + sn;
  const int gnc = gn < HW_ ? gn : (HW_ - 1);   // clamp (garbage cols discarded)
  const float* Xcol = Xb + gnc;

  f32x4 acc[4][4];
#pragma unroll
  for (int i = 0; i < 4; ++i)
#pragma unroll
    for (int j = 0; j < 4; ++j)
      acc[i][j] = (f32x4)0.f;

  const int l15 = lane & 15;
  const int lq  = lane >> 4;

  for (int kk = 0; kk < KIT; ++kk) {
    const int k0 = kk * BK;
    // ---- A tile: 128x32 bf16, async direct-to-LDS, 2 x 16B per thread ----
#pragma unroll
    for (int j = 0; j < 2; ++j) {
      const int idx = tid + j * 256;      // 0..511; dst = base + idx*16 (lane-contig)
      const int m = idx >> 2, q = idx & 3;
      const ushort_t* src = Ab + m * CI_ + k0 + q * 8;
      __builtin_amdgcn_global_load_lds(
          (const __attribute__((address_space(1))) uint_t*)src,
          (__attribute__((address_space(3))) uint_t*)&As[idx * 8], 16, 0, 0);
    }
    // ---- B tile: 32k x 128n fp32 -> transposed [n][k] bf16 ----
#pragma unroll
    for (int j = 0; j < 4; ++j) {
      const int kl = j * 8 + sk4;         // 0,4,...,28
      const float* p = Xcol + (size_t)(k0 + kl) * HW_;
      const float v0 = p[0], v1 = p[HW_], v2 = p[2 * HW_], v3 = p[3 * HW_];
      const uint_t lo = pack_bf16_trunc(v0, v1);
      const uint_t hi = pack_bf16_trunc(v2, v3);
      *(uint2*)&Bs[sn * BS_STRIDE + kl] = make_uint2(lo, hi);
    }
    __syncthreads();
    // ---- MFMA: 16 per wave per K-tile ----
    bf16x8 a[4], bb[4];
#pragma unroll
    for (int mf = 0; mf < 4; ++mf)
      a[mf] = *(const bf16x8*)&As[(wm * 64 + mf * 16 + l15) * BK + lq * 8];
#pragma unroll
    for (int nf = 0; nf < 4; ++nf)
      bb[nf] = *(const bf16x8*)&Bs[(wn * 64 + nf * 16 + l15) * BS_STRIDE + lq * 8];
#pragma unroll
    for (int mf = 0; mf < 4; ++mf)
#pragma unroll
      for (int nf = 0; nf < 4; ++nf)
        acc[mf][nf] = __builtin_amdgcn_mfma_f32_16x16x32_bf16(a[mf], bb[nf],
                                                              acc[mf][nf], 0, 0, 0);
    __syncthreads();
  }

  // ---- Epilogue: C/D layout col=lane&15, row=(lane>>4)*4+reg ----
  float* Ob = Out + (size_t)b * CO_ * HW_;
#pragma unroll
  for (int mf = 0; mf < 4; ++mf) {
#pragma unroll
    for (int nf = 0; nf < 4; ++nf) {
      const int n = nt * BN + wn * 64 + nf * 16 + l15;
      if (n < HW_) {
        const int mbase = mt * BM + wm * 64 + mf * 16 + lq * 4;
#pragma unroll
        for (int r = 0; r < 4; ++r)
          Ob[(size_t)(mbase + r) * HW_ + n] = acc[mf][nf][r];
      }
    }
  }
}

// ---------------------------------------------------------------------------
extern "C" void kernel_launch(void* const* d_in, const int* in_sizes, int n_in,
                              void* d_out, int out_size, void* d_ws, size_t ws_size,
                              hipStream_t stream) {
  const float* x  = (const float*)d_in[0];  // [64,384,28,28] f32
  const float* rw = (const float*)d_in[1];  // [64,8] f32
  const float* w  = (const float*)d_in[2];  // [8,384,384] f32
  float* out = (float*)d_out;               // [64,384,28,28] f32
  ushort_t* agg = (ushort_t*)d_ws;          // [64,384,384] bf16 = 18.9 MB scratch

  agg_kernel<<<dim3((CO_ * CI_) / 512), 256, 0, stream>>>(rw, w, agg);
  moe_gemm<<<dim3(7, 3, B_), 256, 0, stream>>>(x, agg, out);
}

// Round 2
// 175.932 us; speedup vs baseline: 1.0836x; 1.0836x over previous
//
#include <hip/hip_runtime.h>
#include <cstdint>

// Problem constants
#define B_   64
#define CI_  384
#define CO_  384
#define HW_  784
#define E_   8

typedef unsigned short ushort_t;
typedef unsigned int   uint_t;

typedef __attribute__((ext_vector_type(8))) short bf16x8;   // 8 bf16 (4 VGPRs)
typedef __attribute__((ext_vector_type(4))) float f32x4;    // MFMA accumulator

__device__ __forceinline__ ushort_t f2bf_rne(float f) {
  uint_t u = __builtin_bit_cast(uint_t, f);
  u += 0x7fffu + ((u >> 16) & 1u);
  return (ushort_t)(u >> 16);
}

// Pack truncated-bf16 of (f0 -> low ushort, f1 -> high ushort) in one v_perm_b32.
__device__ __forceinline__ uint_t pack_bf16_trunc(float f0, float f1) {
  return __builtin_amdgcn_perm(__builtin_bit_cast(uint_t, f1),   // S0 -> bytes 4..7
                               __builtin_bit_cast(uint_t, f0),   // S1 -> bytes 0..3
                               0x07060302u);                     // {f1.b3,f1.b2,f0.b3,f0.b2}
}

// ---------------------------------------------------------------------------
// Kernel 1: agg[b,o,i] = sum_e r[b,e] * w[e,o,i], stored bf16 into workspace.
// Grid (288, 4): block (x,y) owns 512 consecutive (o,i) elems for 16 b's.
// Weight streamed 4x (18.8 MB) -- trivial; 4.5 blocks/CU hides store latency.
// ---------------------------------------------------------------------------
__global__ __launch_bounds__(256) void agg_kernel(const float* __restrict__ rw,
                                                  const float* __restrict__ w,
                                                  ushort_t* __restrict__ agg) {
  __shared__ float r[B_ * E_];  // 512 routing weights
  const int tid = threadIdx.x;
  r[tid]       = rw[tid];
  r[tid + 256] = rw[tid + 256];
  const int base = blockIdx.x * 512 + tid * 2;  // flat (o,i) pair index
  float2 wv[E_];
#pragma unroll
  for (int e = 0; e < E_; ++e)
    wv[e] = *(const float2*)&w[e * (CO_ * CI_) + base];
  __syncthreads();
  const int b0 = blockIdx.y * 16;
#pragma unroll 4
  for (int bi = 0; bi < 16; ++bi) {
    const int b = b0 + bi;
    float ax = 0.f, ay = 0.f;
#pragma unroll
    for (int e = 0; e < E_; ++e) {
      const float rv = r[b * E_ + e];
      ax += rv * wv[e].x;
      ay += rv * wv[e].y;
    }
    const uint_t v = (uint_t)f2bf_rne(ax) | ((uint_t)f2bf_rne(ay) << 16);
    *(uint_t*)&agg[(size_t)b * (CO_ * CI_) + base] = v;
  }
}

// ---------------------------------------------------------------------------
// Kernel 2: per-sample GEMM  out[b] = agg[b](384x384, bf16) @ x[b](384x784, f32)
// BM=BN=128, BK=32, 256 thr = 4 waves 2x2, wave tile 64x64 (4x4 16x16 frags).
//
// XCD swizzle: grid (8, 168); blockIdx.x == XCD (round-robin linear%8), y packs
// (b>>3, mt, nt) so all 21 tiles of one b share an XCD -> x[b]+agg[b] fetched
// once per XCD (cuts FETCH ~192->~105 MB).
//
// A staged via global_load_lds w=16 into XOR-swizzled slots: slot s holds
// (m=s>>2, q=(s&3)^((s>>3)&3)); frag read slot = m*4 + (lq^((l15>>1)&3)) ->
// 2-way max bank aliasing (free) instead of 8-way on 64B rows.
// B transpose-converted f32->bf16 into [n][k] rows of 80B (2-way, free).
// ---------------------------------------------------------------------------
#define BM 128
#define BN 128
#define BK 32
#define KIT (CI_ / BK)     // 12
#define BS_STRIDE 40       // ushorts per Bs row = 80 B

__global__ __launch_bounds__(256) void moe_gemm(const float* __restrict__ X,
                                                const ushort_t* __restrict__ Agg,
                                                float* __restrict__ Out) {
  __shared__ __align__(16) ushort_t As[BM * BK];         // 512 swizzled 16B slots (8 KB)
  __shared__ __align__(16) ushort_t Bs[BN * BS_STRIDE];  // [n][k], 80B rows (10 KB)

  const int tid  = threadIdx.x;
  const int lane = tid & 63;
  const int wave = tid >> 6;
  const int wm = wave & 1, wn = wave >> 1;

  // XCD-aware decomposition: b = (y/21)*8 + x; rem = y%21; mt = rem/7; nt = rem%7
  const int bx = blockIdx.x;           // 0..7  == XCD id (linear%8 round-robin)
  const int by = blockIdx.y;           // 0..167
  const int bg  = by / 21;
  const int rem = by - bg * 21;
  const int mt  = rem / 7;
  const int nt  = rem - mt * 7;
  const int b   = bg * 8 + bx;

  const ushort_t* Ab = Agg + (size_t)b * CO_ * CI_ + mt * BM * CI_;
  const float*    Xb = X   + (size_t)b * CI_ * HW_;

  // B-staging coords: thread t handles n = t&127, k sub-offset (t>>7)*4
  const int sn  = tid & 127;
  const int sk4 = (tid >> 7) * 4;
  const int gn  = nt * BN + sn;
  const int gnc = gn < HW_ ? gn : (HW_ - 1);   // clamp (garbage cols discarded)
  const float* Xcol = Xb + gnc;

  f32x4 acc[4][4];
#pragma unroll
  for (int i = 0; i < 4; ++i)
#pragma unroll
    for (int j = 0; j < 4; ++j)
      acc[i][j] = (f32x4)0.f;

  const int l15 = lane & 15;
  const int lq  = lane >> 4;
  const int xqA = lq ^ ((l15 >> 1) & 3);   // swizzled q for A-frag reads

  // A-staging source (m,q) for this thread's two slots (s = tid, tid+256):
  // m = s>>2, q = (s&3) ^ ((s>>3)&3)
  const int sm0 = tid >> 2,           sq0 = (tid & 3) ^ ((tid >> 3) & 3);
  const int sm1 = (tid + 256) >> 2,   sq1 = (tid & 3) ^ (((tid + 256) >> 3) & 3);

  for (int kk = 0; kk < KIT; ++kk) {
    const int k0 = kk * BK;
    // ---- A tile: 128x32 bf16, async direct-to-LDS, swizzled slots ----
    {
      const ushort_t* src0 = Ab + sm0 * CI_ + k0 + sq0 * 8;
      __builtin_amdgcn_global_load_lds(
          (const __attribute__((address_space(1))) uint_t*)src0,
          (__attribute__((address_space(3))) uint_t*)&As[tid * 8], 16, 0, 0);
      const ushort_t* src1 = Ab + sm1 * CI_ + k0 + sq1 * 8;
      __builtin_amdgcn_global_load_lds(
          (const __attribute__((address_space(1))) uint_t*)src1,
          (__attribute__((address_space(3))) uint_t*)&As[(tid + 256) * 8], 16, 0, 0);
    }
    // ---- B tile: 32k x 128n fp32 -> transposed [n][k] bf16 ----
#pragma unroll
    for (int j = 0; j < 4; ++j) {
      const int kl = j * 8 + sk4;         // 0,4,...,28
      const float* p = Xcol + (size_t)(k0 + kl) * HW_;
      const float v0 = p[0], v1 = p[HW_], v2 = p[2 * HW_], v3 = p[3 * HW_];
      const uint_t lo = pack_bf16_trunc(v0, v1);
      const uint_t hi = pack_bf16_trunc(v2, v3);
      *(uint2*)&Bs[sn * BS_STRIDE + kl] = make_uint2(lo, hi);
    }
    __syncthreads();
    // ---- MFMA: 16 per wave per K-tile ----
    bf16x8 a[4], bb[4];
#pragma unroll
    for (int mf = 0; mf < 4; ++mf) {
      const int m = wm * 64 + mf * 16 + l15;
      a[mf] = *(const bf16x8*)&As[(m * 4 + xqA) * 8];
    }
#pragma unroll
    for (int nf = 0; nf < 4; ++nf)
      bb[nf] = *(const bf16x8*)&Bs[(wn * 64 + nf * 16 + l15) * BS_STRIDE + lq * 8];
#pragma unroll
    for (int mf = 0; mf < 4; ++mf)
#pragma unroll
      for (int nf = 0; nf < 4; ++nf)
        acc[mf][nf] = __builtin_amdgcn_mfma_f32_16x16x32_bf16(a[mf], bb[nf],
                                                              acc[mf][nf], 0, 0, 0);
    __syncthreads();
  }

  // ---- Epilogue: C/D layout col=lane&15, row=(lane>>4)*4+reg ----
  float* Ob = Out + (size_t)b * CO_ * HW_;
#pragma unroll
  for (int mf = 0; mf < 4; ++mf) {
#pragma unroll
    for (int nf = 0; nf < 4; ++nf) {
      const int n = nt * BN + wn * 64 + nf * 16 + l15;
      if (n < HW_) {
        const int mbase = mt * BM + wm * 64 + mf * 16 + lq * 4;
#pragma unroll
        for (int r = 0; r < 4; ++r)
          Ob[(size_t)(mbase + r) * HW_ + n] = acc[mf][nf][r];
      }
    }
  }
}

// ---------------------------------------------------------------------------
extern "C" void kernel_launch(void* const* d_in, const int* in_sizes, int n_in,
                              void* d_out, int out_size, void* d_ws, size_t ws_size,
                              hipStream_t stream) {
  const float* x  = (const float*)d_in[0];  // [64,384,28,28] f32
  const float* rw = (const float*)d_in[1];  // [64,8] f32
  const float* w  = (const float*)d_in[2];  // [8,384,384] f32
  float* out = (float*)d_out;               // [64,384,28,28] f32
  ushort_t* agg = (ushort_t*)d_ws;          // [64,384,384] bf16 = 18.9 MB scratch

  agg_kernel<<<dim3((CO_ * CI_) / 512, 4), 256, 0, stream>>>(rw, w, agg);
  moe_gemm<<<dim3(8, 168), 256, 0, stream>>>(x, agg, out);
}